// Round 4
// baseline (1832.577 us; speedup 1.0000x reference)
//
#include <hip/hip_runtime.h>
#include <hip/hip_bf16.h>

#define NN 50000
#define NE 800000
#define NG 3
#define NB 256
#define NSCB 196  // ceil(NN/256)

#define OFF_FUSED ((size_t)0)
#define OFF_EMB   ((size_t)NN * 64)
#define OFF_G     (OFF_EMB + (size_t)NN * 256)
#define OFF_HID   (OFF_G + (size_t)NB * 64)
#define OFF_ATTN  (OFF_HID + (size_t)3 * NN * 64)

typedef unsigned short u16;

__device__ __forceinline__ float bf2f(u16 u) {
  union { unsigned int i; float f; } v; v.i = ((unsigned int)u) << 16; return v.f;
}
__device__ __forceinline__ u16 f2bf(float f) {
  unsigned int x = __float_as_uint(f);
  unsigned int r = (x + 0x7FFFu + ((x >> 16) & 1u)) >> 16;
  return (u16)r;
}
__device__ __forceinline__ float ldf(const void* p, size_t i, int f32) {
  return f32 ? ((const float*)p)[i] : bf2f(((const u16*)p)[i]);
}
__device__ __forceinline__ int ld_src(const void* ei, int e, int i64) {
  return i64 ? (int)((const long long*)ei)[e] : ((const int*)ei)[e];
}
__device__ __forceinline__ int ld_dst(const void* ei, int e, int i64) {
  return i64 ? (int)((const long long*)ei)[(size_t)NE + e] : ((const int*)ei)[(size_t)NE + e];
}

// ---- dtype detection ----
__global__ void k_detect(const void* x, const void* ei, int* flags) {
  if (threadIdx.x != 0 || blockIdx.x != 0) return;
  const u16* xw = (const u16*)x;
  int sane = 0;
  for (int i = 0; i < 64; ++i) {
    unsigned ex = (xw[2 * i] >> 7) & 0xFF;  // exponent field if bf16
    sane += (ex >= 96 && ex <= 141);
  }
  flags[0] = (sane < 48) ? 1 : 0;  // 1 => inputs are float32
  const int* e32 = (const int*)ei;
  int zeros = 0;
  for (int t = 1; t < 32; t += 2) zeros += (e32[t] == 0);
  flags[1] = (zeros >= 12) ? 1 : 0;  // 1 => edge_index is int64
}

// ---- degree accumulation ----
__global__ void k_deg(const void* ei, const void* aew, const int* __restrict__ flags,
                      float* __restrict__ deg, unsigned* __restrict__ cnt) {
  int e = blockIdx.x * 256 + threadIdx.x;
  if (e >= NE) return;
  int f32 = flags[0], i64 = flags[1];
  int d = ld_dst(ei, e, i64);
  atomicAdd(&cnt[d], 1u);
  atomicAdd(&deg[d],          ldf(aew, e, f32));
  atomicAdd(&deg[NN + d],     ldf(aew, (size_t)NE + e, f32));
  atomicAdd(&deg[2 * NN + d], ldf(aew, (size_t)2 * NE + e, f32));
}

__global__ void k_dis(float* __restrict__ deg, const unsigned* __restrict__ cnt,
                      float* __restrict__ dis2) {
  int i = blockIdx.x * 256 + threadIdx.x;
  if (i < 3 * NN) deg[i] = rsqrtf(deg[i] + 1.0f);
  if (i < NN) dis2[i] = rsqrtf((float)cnt[i] + 1.0f);
}

// ---- 3-phase exclusive scan of cnt -> row_ptr ----
__global__ __launch_bounds__(256) void k_sc1(const unsigned* __restrict__ cnt,
                                             unsigned* __restrict__ bsum) {
  int b = blockIdx.x, tid = threadIdx.x, i = b * 256 + tid;
  unsigned v = (i < NN) ? cnt[i] : 0u;
  #pragma unroll
  for (int off = 32; off > 0; off >>= 1) v += __shfl_down(v, off);
  __shared__ unsigned w4[4];
  if ((tid & 63) == 0) w4[tid >> 6] = v;
  __syncthreads();
  if (tid == 0) bsum[b] = w4[0] + w4[1] + w4[2] + w4[3];
}
__global__ __launch_bounds__(256) void k_sc2(const unsigned* __restrict__ bsum,
                                             unsigned* __restrict__ boff,
                                             unsigned* __restrict__ row_ptr) {
  int tid = threadIdx.x, lane = tid & 63, w = tid >> 6;
  unsigned v = (tid < NSCB) ? bsum[tid] : 0u;
  unsigned x = v;
  #pragma unroll
  for (int off = 1; off < 64; off <<= 1) {
    unsigned y = __shfl_up(x, off);
    if (lane >= off) x += y;
  }
  __shared__ unsigned w4[4];
  if (lane == 63) w4[w] = x;
  __syncthreads();
  unsigned woff = 0;
  #pragma unroll
  for (int k = 0; k < 4; ++k) woff += (k < w) ? w4[k] : 0u;
  if (tid < NSCB) boff[tid] = woff + x - v;
  if (tid == 255) row_ptr[NN] = woff + x;
}
__global__ __launch_bounds__(256) void k_sc3(const unsigned* __restrict__ cnt,
                                             const unsigned* __restrict__ boff,
                                             unsigned* __restrict__ row_ptr) {
  int b = blockIdx.x, tid = threadIdx.x, lane = tid & 63, w = tid >> 6;
  int i = b * 256 + tid;
  unsigned v = (i < NN) ? cnt[i] : 0u;
  unsigned x = v;
  #pragma unroll
  for (int off = 1; off < 64; off <<= 1) {
    unsigned y = __shfl_up(x, off);
    if (lane >= off) x += y;
  }
  __shared__ unsigned w4[4];
  if (lane == 63) w4[w] = x;
  __syncthreads();
  unsigned woff = 0;
  #pragma unroll
  for (int k = 0; k < 4; ++k) woff += (k < w) ? w4[k] : 0u;
  if (i < NN) row_ptr[i] = boff[b] + woff + x - v;
}

// ---- CSR fill ----
__global__ void k_fill(const void* ei, const int* __restrict__ flags,
                       const unsigned* __restrict__ row_ptr,
                       unsigned* __restrict__ fill, unsigned* __restrict__ col) {
  int e = blockIdx.x * 256 + threadIdx.x;
  if (e >= NE) return;
  int d = ld_dst(ei, e, flags[1]);
  unsigned pos = row_ptr[d] + atomicAdd(&fill[d], 1u);
  col[pos] = (unsigned)e;
}

// ---- h1[N,64] = x[N,256] @ W1[256,64] via LDS + shfl matvec ----
__global__ __launch_bounds__(256) void k_h1(const void* x, const void* W1,
                                            const int* __restrict__ flags,
                                            float* __restrict__ h1) {
  __shared__ u16 W1L[256 * 64];
  int tid = threadIdx.x;
  int f32 = flags[0];
  for (int i = tid; i < 256 * 64; i += 256)
    W1L[i] = f32 ? f2bf(((const float*)W1)[i]) : ((const u16*)W1)[i];
  __syncthreads();
  int wid = tid >> 6, lane = tid & 63;
  int n = blockIdx.x * 4 + wid;
  if (n >= NN) return;
  float xv[4];
  #pragma unroll
  for (int kk = 0; kk < 4; ++kk) xv[kk] = ldf(x, (size_t)n * 256 + kk * 64 + lane, f32);
  float acc = 0.f;
  #pragma unroll
  for (int kk = 0; kk < 4; ++kk) {
    for (int j = 0; j < 64; ++j) {
      float a = __shfl(xv[kk], j);
      acc += a * bf2f(W1L[(kk * 64 + j) * 64 + lane]);
    }
  }
  h1[(size_t)n * 64 + lane] = acc;
}

// ---- gather layer1 (3 graphs) + attention fusion ----
__global__ __launch_bounds__(256) void k_hidden(
    const float* __restrict__ h1, const void* ei,
    const unsigned* __restrict__ row_ptr, const unsigned* __restrict__ col,
    const void* aew, const float* __restrict__ deg_dis,
    const void* Wf, const void* bfv, const void* qf, const void* b1,
    const int* __restrict__ flags, float* __restrict__ dout) {
  __shared__ float WfL[3 * 64 * 64];
  __shared__ float qfL[192], bfL[192], b1L[64];
  int tid = threadIdx.x;
  int f32 = flags[0], i64 = flags[1];
  for (int i = tid; i < 3 * 64 * 64; i += 256) WfL[i] = ldf(Wf, i, f32);
  if (tid < 192) { qfL[tid] = ldf(qf, tid, f32); bfL[tid] = ldf(bfv, tid, f32); }
  if (tid < 64) b1L[tid] = ldf(b1, tid, f32);
  __syncthreads();
  int wid = tid >> 6, lane = tid & 63;
  int n = blockIdx.x * 4 + wid;
  if (n >= NN) return;

  float dd0 = deg_dis[n], dd1 = deg_dis[NN + n], dd2 = deg_dis[2 * NN + n];
  float hv = h1[(size_t)n * 64 + lane];
  float acc0 = hv * dd0 * dd0, acc1 = hv * dd1 * dd1, acc2 = hv * dd2 * dd2;

  unsigned beg = row_ptr[n], end = row_ptr[n + 1];
  for (unsigned base = beg; base < end; base += 64) {
    unsigned rem = end - base;
    int m = (rem > 64u) ? 64 : (int)rem;
    int s = 0; float w0 = 0.f, w1 = 0.f, w2 = 0.f;
    if (lane < m) {
      unsigned e = col[base + lane];
      s = ld_src(ei, (int)e, i64);
      w0 = deg_dis[s]          * ldf(aew, e, f32)                  * dd0;
      w1 = deg_dis[NN + s]     * ldf(aew, (size_t)NE + e, f32)     * dd1;
      w2 = deg_dis[2 * NN + s] * ldf(aew, (size_t)2 * NE + e, f32) * dd2;
    }
    for (int j = 0; j < m; ++j) {
      int sj = __shfl(s, j);
      float hs = h1[(size_t)sj * 64 + lane];
      acc0 += hs * __shfl(w0, j);
      acc1 += hs * __shfl(w1, j);
      acc2 += hs * __shfl(w2, j);
    }
  }
  float b1v = b1L[lane];
  float hid0 = fmaxf(acc0 + b1v, 0.f);
  float hid1 = fmaxf(acc1 + b1v, 0.f);
  float hid2 = fmaxf(acc2 + b1v, 0.f);
  dout[OFF_HID + ((size_t)0 * NN + n) * 64 + lane] = hid0;
  dout[OFF_HID + ((size_t)1 * NN + n) * 64 + lane] = hid1;
  dout[OFF_HID + ((size_t)2 * NN + n) * 64 + lane] = hid2;

  float t0 = bfL[lane], t1 = bfL[64 + lane], t2 = bfL[128 + lane];
  for (int k = 0; k < 64; ++k) {
    float h0 = __shfl(hid0, k), h1v = __shfl(hid1, k), h2v = __shfl(hid2, k);
    t0 += h0  * WfL[k * 64 + lane];
    t1 += h1v * WfL[4096 + k * 64 + lane];
    t2 += h2v * WfL[8192 + k * 64 + lane];
  }
  t0 = tanhf(t0); t1 = tanhf(t1); t2 = tanhf(t2);
  float s0 = t0 * qfL[lane], s1 = t1 * qfL[64 + lane], s2 = t2 * qfL[128 + lane];
  #pragma unroll
  for (int off = 32; off > 0; off >>= 1) {
    s0 += __shfl_xor(s0, off);
    s1 += __shfl_xor(s1, off);
    s2 += __shfl_xor(s2, off);
  }
  float mx = fmaxf(s0, fmaxf(s1, s2));
  float e0 = expf(s0 - mx), e1 = expf(s1 - mx), e2 = expf(s2 - mx);
  float inv = 1.0f / (e0 + e1 + e2);
  float a0 = e0 * inv, a1 = e1 * inv, a2 = e2 * inv;
  float fv = a0 * hid0 + a1 * hid1 + a2 * hid2;
  dout[OFF_FUSED + (size_t)n * 64 + lane] = fv;
  if (lane < 3) dout[OFF_ATTN + (size_t)n * 3 + lane] =
                    (lane == 0 ? a0 : (lane == 1 ? a1 : a2));
}

// ---- layer2 fused: agg = sym-aggregate(fused) in 64-dim, emb = relu(agg@W2+b2) ----
__global__ __launch_bounds__(256) void k_emb(
    const void* ei,
    const unsigned* __restrict__ row_ptr, const unsigned* __restrict__ col,
    const float* __restrict__ dis2, const void* W2, const void* b2,
    const int* __restrict__ flags, float* __restrict__ dout) {
  __shared__ u16 W2L[64 * 256];
  __shared__ float b2L[256];
  int tid = threadIdx.x;
  int f32 = flags[0], i64 = flags[1];
  for (int i = tid; i < 64 * 256; i += 256)
    W2L[i] = f32 ? f2bf(((const float*)W2)[i]) : ((const u16*)W2)[i];
  b2L[tid] = ldf(b2, tid, f32);
  __syncthreads();
  const float* fused = dout + OFF_FUSED;
  int wid = tid >> 6, lane = tid & 63;
  int n = blockIdx.x * 4 + wid;
  if (n >= NN) return;
  float dd = dis2[n];
  float av = fused[(size_t)n * 64 + lane] * dd * dd;
  unsigned beg = row_ptr[n], end = row_ptr[n + 1];
  for (unsigned base = beg; base < end; base += 64) {
    unsigned rem = end - base;
    int m = (rem > 64u) ? 64 : (int)rem;
    int s = 0; float w = 0.f;
    if (lane < m) {
      unsigned e = col[base + lane];
      s = ld_src(ei, (int)e, i64);
      w = dis2[s] * dd;
    }
    for (int j = 0; j < m; ++j) {
      int sj = __shfl(s, j);
      av += fused[(size_t)sj * 64 + lane] * __shfl(w, j);
    }
  }
  float acc[4] = {b2L[lane * 4], b2L[lane * 4 + 1], b2L[lane * 4 + 2], b2L[lane * 4 + 3]};
  for (int k = 0; k < 64; ++k) {
    float a = __shfl(av, k);
    ushort4 wv = *(const ushort4*)(&W2L[k * 256 + lane * 4]);
    acc[0] += a * bf2f(wv.x); acc[1] += a * bf2f(wv.y);
    acc[2] += a * bf2f(wv.z); acc[3] += a * bf2f(wv.w);
  }
  #pragma unroll
  for (int c = 0; c < 4; ++c)
    dout[OFF_EMB + (size_t)n * 256 + lane * 4 + c] = fmaxf(acc[c], 0.f);
}

// ---- vsum = graph_neigh @ fused (split-K) + row sums ----
#define VS_BG 16
#define VS_SPLIT 98
#define VS_CHUNK 512
__global__ __launch_bounds__(64) void k_vsum(const void* gn,
                                             const float* __restrict__ dout,
                                             const int* __restrict__ flags,
                                             float* __restrict__ vsum,
                                             float* __restrict__ row_sum) {
  const float* fused = dout + OFF_FUSED;
  int lane = threadIdx.x;
  int f32 = flags[0];
  int bg = blockIdx.x / VS_SPLIT;
  int sp = blockIdx.x % VS_SPLIT;
  int b0 = bg * VS_BG;
  int n0 = sp * VS_CHUNK;
  int n1 = (n0 + VS_CHUNK < NN) ? n0 + VS_CHUNK : NN;
  float acc[VS_BG], rs[VS_BG];
  #pragma unroll
  for (int i = 0; i < VS_BG; ++i) { acc[i] = 0.f; rs[i] = 0.f; }
  for (int n = n0; n < n1; ++n) {
    float fv = fused[(size_t)n * 64 + lane];
    #pragma unroll
    for (int bb = 0; bb < VS_BG; ++bb) {
      float g = ldf(gn, (size_t)(b0 + bb) * NN + n, f32);
      acc[bb] += g * fv;
      rs[bb] += g;
    }
  }
  #pragma unroll
  for (int bb = 0; bb < VS_BG; ++bb) {
    atomicAdd(&vsum[(b0 + bb) * 64 + lane], acc[bb]);
    if (lane == 0) atomicAdd(&row_sum[b0 + bb], rs[bb]);
  }
}

__global__ __launch_bounds__(64) void k_gfinal(const float* __restrict__ vsum,
                                               const float* __restrict__ row_sum,
                                               float* __restrict__ dout) {
  int b = blockIdx.x, j = threadIdx.x;
  float v = vsum[b * 64 + j] / row_sum[b];
  float sq = v * v;
  #pragma unroll
  for (int off = 32; off > 0; off >>= 1) sq += __shfl_xor(sq, off);
  float nrm = sqrtf(sq);
  dout[OFF_G + (size_t)b * 64 + j] = v / fmaxf(nrm, 1e-12f);
}

extern "C" void kernel_launch(void* const* d_in, const int* in_sizes, int n_in,
                              void* d_out, int out_size, void* d_ws, size_t ws_size,
                              hipStream_t stream) {
  const void* x   = d_in[0];
  const void* ei  = d_in[1];
  const void* gn  = d_in[2];
  const void* aew = d_in[3];
  const void* W1  = d_in[4];
  const void* b1  = d_in[5];
  const void* W2  = d_in[6];
  const void* b2  = d_in[7];
  const void* Wf  = d_in[8];
  const void* bfv = d_in[9];
  const void* qf  = d_in[10];

  char* ws = (char*)d_ws;
  size_t off = 0;
  auto alloc = [&](size_t bytes) -> void* {
    void* p = ws + off;
    off += (bytes + 255) & ~(size_t)255;
    return p;
  };
  // zero-init region
  float*    deg     = (float*)alloc((size_t)3 * NN * 4);
  unsigned* cnt     = (unsigned*)alloc((size_t)NN * 4);
  unsigned* fill    = (unsigned*)alloc((size_t)NN * 4);
  float*    vsum    = (float*)alloc((size_t)NB * 64 * 4);
  float*    row_sum = (float*)alloc((size_t)NB * 4);
  size_t zero_bytes = off;
  int*      flags   = (int*)alloc(64);
  float*    dis2    = (float*)alloc((size_t)NN * 4);
  unsigned* row_ptr = (unsigned*)alloc((size_t)(NN + 1) * 4);
  unsigned* bsum    = (unsigned*)alloc((size_t)NSCB * 4);
  unsigned* boff    = (unsigned*)alloc((size_t)NSCB * 4);
  unsigned* col     = (unsigned*)alloc((size_t)NE * 4);
  float*    h1      = (float*)alloc((size_t)NN * 64 * 4);

  float* dout = (float*)d_out;

  hipMemsetAsync(d_ws, 0, zero_bytes, stream);
  k_detect<<<1, 64, 0, stream>>>(x, ei, flags);
  k_deg<<<(NE + 255) / 256, 256, 0, stream>>>(ei, aew, flags, deg, cnt);
  k_dis<<<(3 * NN + 255) / 256, 256, 0, stream>>>(deg, cnt, dis2);
  k_sc1<<<NSCB, 256, 0, stream>>>(cnt, bsum);
  k_sc2<<<1, 256, 0, stream>>>(bsum, boff, row_ptr);
  k_sc3<<<NSCB, 256, 0, stream>>>(cnt, boff, row_ptr);
  k_fill<<<(NE + 255) / 256, 256, 0, stream>>>(ei, flags, row_ptr, fill, col);
  k_h1<<<(NN + 3) / 4, 256, 0, stream>>>(x, W1, flags, h1);
  k_hidden<<<(NN + 3) / 4, 256, 0, stream>>>(h1, ei, row_ptr, col, aew, deg,
                                             Wf, bfv, qf, b1, flags, dout);
  k_emb<<<(NN + 3) / 4, 256, 0, stream>>>(ei, row_ptr, col, dis2, W2, b2, flags, dout);
  k_vsum<<<(NB / VS_BG) * VS_SPLIT, 64, 0, stream>>>(gn, dout, flags, vsum, row_sum);
  k_gfinal<<<NB, 64, 0, stream>>>(vsum, row_sum, dout);
}